// Round 10
// baseline (124.383 us; speedup 1.0000x reference)
//
#include <hip/hip_runtime.h>

// MLP: 64 × (Linear(5,5)+ReLU) then Linear(5,1), BATCH = 1048576 rows.
// fp32 VALU compute-bound; scalar v_fma_f32 IS the fp32 peak on CDNA4
// (157.3 TF == SIMD-32 scalar rate; packed f2 scalarizes, correctly).
//
// R10 = minimal-instruction scalar form at maximal occupancy:
//  - 2 rows/thread -> 2048 blocks = 8 blocks/CU = 32 waves/CU (HW cap).
//  - bias enters as the FIRST fma's VOP3 addend: 25 fma + 5 max per row,
//    60 VALU/layer/thread — the scalar floor. No init movs.
//  - weights: 8 wave-uniform dwordx4 loads/layer from a prep'd padded
//    [64][32]-float layout (L1-resident, broadcast). VMEM pipe, co-issued.
//  - fully unrolled layer loop: const offsets, SSA renames, no branches.
// Evidence base (R2-R9): every low-level trick (SGPR games, op_sel asm,
// s_load islands, prefetch dbuf, LDS tiles) regressed; the clean scalar
// shape is what this compiler schedules best. Model: dur ≈ 0.852 ×
// slots/row / VALUBusy -> 34 slots @ ~0.83 busy ≈ 35 µs.

#define MLP_DEPTH 64
#define MLP_D 5
#define ROWS 2

// d_ws: layer l at [l*32]: k<25 -> W[j*5+i] (j-major); 25..29 -> b[j];
// 30,31 pad. Tail at [2048]: W_out[0..4], b_out, pad, pad. 2056 floats.
__global__ __launch_bounds__(256) void MLP_prep_kernel(
    const float* __restrict__ Ws, const float* __restrict__ bs,
    const float* __restrict__ W_out, const float* __restrict__ b_out,
    float* __restrict__ ws)
{
    const int idx = blockIdx.x * blockDim.x + threadIdx.x;
    if (idx < MLP_DEPTH * 32) {
        const int l = idx >> 5, k = idx & 31;
        float v = 0.0f;
        if (k < 25) v = Ws[l * 25 + k];
        else if (k < 30) v = bs[l * MLP_D + (k - 25)];
        ws[idx] = v;
    } else if (idx < MLP_DEPTH * 32 + 8) {
        const int k = idx - MLP_DEPTH * 32;
        float v = 0.0f;
        if (k < MLP_D) v = W_out[k];
        else if (k == MLP_D) v = b_out[0];
        ws[idx] = v;
    }
}

typedef float f2v __attribute__((ext_vector_type(2)));

__global__ __launch_bounds__(256) void MLP_89687507075104_kernel(
    const float* __restrict__ x,      // [n, 5]
    const float4* __restrict__ wq,    // prep'd: 8 float4/layer + 2 tail
    float* __restrict__ out,          // [n]
    int n)
{
    const int t = blockIdx.x * blockDim.x + threadIdx.x;
    const long row0 = (long)t * ROWS;
    if (row0 >= n) return;

    // rows row0,row0+1 = 10 contiguous floats (40 B, 8B-aligned f2 loads).
    const f2v* xp = reinterpret_cast<const f2v*>(x + row0 * MLP_D);
    const f2v v0 = xp[0], v1 = xp[1], v2 = xp[2], v3 = xp[3], v4 = xp[4];
    float h[ROWS][MLP_D];
    h[0][0] = v0.x; h[0][1] = v0.y; h[0][2] = v1.x; h[0][3] = v1.y; h[0][4] = v2.x;
    h[1][0] = v2.y; h[1][1] = v3.x; h[1][2] = v3.y; h[1][3] = v4.x; h[1][4] = v4.y;

#pragma unroll
    for (int l = 0; l < MLP_DEPTH; ++l) {
        // 8 wave-uniform dwordx4 loads; weights+biases for this layer.
        const float4* wp = wq + l * 8;
        float W[32];
#pragma unroll
        for (int m = 0; m < 8; ++m) {
            const float4 c = wp[m];
            W[4*m+0] = c.x; W[4*m+1] = c.y; W[4*m+2] = c.z; W[4*m+3] = c.w;
        }
        float a[ROWS][MLP_D];
#pragma unroll
        for (int r = 0; r < ROWS; ++r) {
#pragma unroll
            for (int j = 0; j < MLP_D; ++j) {
                // bias = first fma's VOP3 addend: no init instruction.
                float acc = fmaf(h[r][0], W[j * MLP_D + 0], W[25 + j]);
#pragma unroll
                for (int i = 1; i < MLP_D; ++i)
                    acc = fmaf(h[r][i], W[j * MLP_D + i], acc);
                a[r][j] = acc;
            }
        }
#pragma unroll
        for (int r = 0; r < ROWS; ++r)
#pragma unroll
            for (int j = 0; j < MLP_D; ++j)
                h[r][j] = fmaxf(a[r][j], 0.0f);
    }

    // Output layer: Linear(5,1). Tail at wq[512..513].
    const float4 c0 = wq[MLP_DEPTH * 8 + 0];
    const float4 c1 = wq[MLP_DEPTH * 8 + 1];
    f2v o;
#pragma unroll
    for (int r = 0; r < ROWS; ++r) {
        float acc = fmaf(h[r][0], c0.x, c1.y);   // b_out as addend
        acc = fmaf(h[r][1], c0.y, acc);
        acc = fmaf(h[r][2], c0.z, acc);
        acc = fmaf(h[r][3], c0.w, acc);
        acc = fmaf(h[r][4], c1.x, acc);
        o[r] = acc;
    }
    *reinterpret_cast<f2v*>(out + row0) = o;
}

extern "C" void kernel_launch(void* const* d_in, const int* in_sizes, int n_in,
                              void* d_out, int out_size, void* d_ws, size_t ws_size,
                              hipStream_t stream) {
    const float* x     = (const float*)d_in[0];
    const float* Ws    = (const float*)d_in[1];
    const float* bs    = (const float*)d_in[2];
    const float* W_out = (const float*)d_in[3];
    const float* b_out = (const float*)d_in[4];
    float* out = (float*)d_out;
    float* ws  = (float*)d_ws;   // needs 2056*4 = 8224 B

    const int n = in_sizes[0] / MLP_D;  // batch rows (1048576)

    const int nprep = MLP_DEPTH * 32 + 8;
    MLP_prep_kernel<<<(nprep + 255) / 256, 256, 0, stream>>>(Ws, bs, W_out, b_out, ws);

    const int block = 256;
    const int threads_needed = (n + ROWS - 1) / ROWS;
    const int grid = (threads_needed + block - 1) / block;  // 2048
    MLP_89687507075104_kernel<<<grid, block, 0, stream>>>(
        x, reinterpret_cast<const float4*>(ws), out, n);
}